// Round 1
// baseline (67.338 us; speedup 1.0000x reference)
//
#include <hip/hip_runtime.h>

// Quanvolution: 8112 independent 9-qubit circuits.
// Key algebra (verified by hand against physical probes):
//  - embedding RX(p_i) and layer-0 RX(w0_i) fuse: RX(p_i + w0_i); initial state
//    is a product state: t[j] = (-i)^popc(j) * prod_i (j_i ? sin : cos)((p+w0)/2)
//  - CNOT ring = linear basis map |x> -> |Ax> over GF(2); skip data movement and
//    relabel instead. Layer-1 RX on qubit q becomes a butterfly with mask =
//    column q of A^-1: {0x003,0x006,0x00C,0x018,0x030,0x060,0x0C0,0x180,0x103}
//  - second ring folds into measurement: <Z_f> = sum_j (-1)^popc(row_f(A^2)&j)|t[j]|^2,
//    rows(A^2) f=0..3: {0x154,0x1FD,0x1FA,0x1F5}
// Layout: j = (k<<6)|lane -> 8 complex amps per lane in VGPRs, one wave per
// (pixel, channel) circuit; block = 192 thr = 3 waves = 3 channels of one pixel.

static constexpr int BQ = 4;
static constexpr int CH = 3;
static constexpr int HOUT = 26;
static constexpr int WOUT = 26;

__device__ __forceinline__ float shflx(float v, int m) {
  return __shfl_xor(v, m, 64);
}

__global__ __launch_bounds__(192) void quanv_kernel(
    const float* __restrict__ x,   // (4,3,28,28) f32
    const float* __restrict__ w,   // (2,9) f32
    float* __restrict__ out)       // (4,4,26,26) f32
{
  __shared__ float sm[CH * 4];

  const int pix  = blockIdx.x;            // 0..2703
  const int b    = pix / (HOUT * WOUT);
  const int r    = pix % (HOUT * WOUT);
  const int oy   = r / WOUT;
  const int ox   = r % WOUT;
  const int ch   = threadIdx.x >> 6;      // 0..2 (wave id = channel)
  const int lane = threadIdx.x & 63;

  // ---- angles: combined first rotation theta_i = (p_i + w0_i)/2 ----
  float ci[9], si[9];
#pragma unroll
  for (int i = 0; i < 9; ++i) {
    const int dy = i / 3, dx = i % 3;
    const float p  = x[((b * CH + ch) * 28 + (oy + dy)) * 28 + (ox + dx)];
    const float th = 0.5f * (p + w[i]);
    ci[i] = __cosf(th);
    si[i] = __sinf(th);
  }
  // layer-1 half-angles (patch-independent)
  float c1[9], s1[9];
#pragma unroll
  for (int q = 0; q < 9; ++q) {
    const float th = 0.5f * w[9 + q];
    c1[q] = __cosf(th);
    s1[q] = __sinf(th);
  }

  // ---- init product state ----
  float plo = 1.f;
#pragma unroll
  for (int q = 0; q < 6; ++q)
    plo *= ((lane >> q) & 1) ? si[q] : ci[q];
  const int pclo = __popc(lane);

  float tr[8], ti[8];
#pragma unroll
  for (int k = 0; k < 8; ++k) {
    const float r8 = plo * ((k & 1) ? si[6] : ci[6])
                         * ((k & 2) ? si[7] : ci[7])
                         * ((k & 4) ? si[8] : ci[8]);
    const int pc = (pclo + __popc(k)) & 3;           // phase (-i)^pc
    tr[k] = (pc == 0) ? r8 : ((pc == 2) ? -r8 : 0.f);
    ti[k] = (pc == 3) ? r8 : ((pc == 1) ? -r8 : 0.f);
  }

  // ---- 9 layer-1 butterfly passes (masks = columns of A^-1) ----
  // mask bits [5:0] -> lane xor (shuffle), bits [8:6] -> register xor
  constexpr int LXm[9] = {3, 6, 12, 24, 48, 32, 0, 0, 3};
  constexpr int KXm[9] = {0, 0, 0,  0,  0,  1,  3, 6, 4};
#pragma unroll
  for (int q = 0; q < 9; ++q) {
    const float c = c1[q], s = s1[q];
    float pr[8], pim[8];
#pragma unroll
    for (int k = 0; k < 8; ++k) {
      float vr = tr[k ^ KXm[q]];
      float vi = ti[k ^ KXm[q]];
      if (LXm[q] != 0) {
        vr = shflx(vr, LXm[q]);
        vi = shflx(vi, LXm[q]);
      }
      pr[k] = vr;
      pim[k] = vi;
    }
    // t' = c*t - i*s*t_partner  (RX butterfly is symmetric in the pair)
#pragma unroll
    for (int k = 0; k < 8; ++k) {
      const float ntr = c * tr[k] + s * pim[k];
      const float nti = c * ti[k] - s * pr[k];
      tr[k] = ntr;
      ti[k] = nti;
    }
  }

  // ---- probabilities & 4 filter expectations (rows of A^2) ----
  float prob[8];
#pragma unroll
  for (int k = 0; k < 8; ++k) prob[k] = tr[k] * tr[k] + ti[k] * ti[k];

  constexpr int ROW[4] = {0x154, 0x1FD, 0x1FA, 0x1F5};
  float z[4];
#pragma unroll
  for (int f = 0; f < 4; ++f) {
    const int hi = ROW[f] >> 6;
    const int lo = ROW[f] & 63;
    float acc = 0.f;
#pragma unroll
    for (int k = 0; k < 8; ++k)
      acc += (__popc(hi & k) & 1) ? -prob[k] : prob[k];
    z[f] = (__popc(lo & lane) & 1) ? -acc : acc;
  }

  // ---- wave butterfly reduction (all lanes end with the total) ----
#pragma unroll
  for (int m = 1; m < 64; m <<= 1) {
#pragma unroll
    for (int f = 0; f < 4; ++f) z[f] += shflx(z[f], m);
  }
  if (lane == 0) {
#pragma unroll
    for (int f = 0; f < 4; ++f) sm[ch * 4 + f] = z[f];
  }
  __syncthreads();

  // ---- channel mean, write (B,F,26,26) ----
  if (threadIdx.x < 4) {
    const int f = threadIdx.x;
    const float v = (sm[f] + sm[4 + f] + sm[8 + f]) * (1.f / 3.f);
    out[((b * 4 + f) * HOUT + oy) * WOUT + ox] = v;
  }
}

extern "C" void kernel_launch(void* const* d_in, const int* in_sizes, int n_in,
                              void* d_out, int out_size, void* d_ws, size_t ws_size,
                              hipStream_t stream) {
  const float* x = (const float*)d_in[0];
  const float* w = (const float*)d_in[1];
  float* out = (float*)d_out;
  dim3 grid(BQ * HOUT * WOUT);   // 2704 pixel blocks
  dim3 block(192);               // 3 waves = 3 channels
  hipLaunchKernelGGL(quanv_kernel, grid, block, 0, stream, x, w, out);
}